// Round 1
// baseline (2220.939 us; speedup 1.0000x reference)
//
#include <hip/hip_runtime.h>
#include <hip/hip_bf16.h>
#include <math.h>

#define I48 0.14433756729740643f  // 1/sqrt(48)

__device__ __forceinline__ float silu_f(float x){ return x / (1.f + __expf(-x)); }

// ---------------- time embedding (1 block, 128 thr) ----------------
__global__ void k_temb(const float* __restrict__ t_in,
                       const float* __restrict__ w1, const float* __restrict__ b1,
                       const float* __restrict__ w2, const float* __restrict__ b2,
                       const float* __restrict__ g,  const float* __restrict__ b,
                       float* __restrict__ temb){
  __shared__ float emb[64], h1[128], red[128];
  __shared__ float s_mu, s_rs;
  int t = threadIdx.x;
  float tv = t_in[0];
  if (t < 64){
    int i = t & 31;
    float fr = __expf((float)i * (-9.210340371976184f/31.f)); // -ln(10000)/31
    float a = tv * fr;
    emb[t] = (t < 32) ? sinf(a) : cosf(a);
  }
  __syncthreads();
  {
    float z = b1[t];
    for (int i=0;i<64;i++) z += emb[i]*w1[i*128+t];
    h1[t] = silu_f(z);
  }
  __syncthreads();
  float tp = 0.f;
  if (t < 64){
    tp = b2[t];
    for (int j=0;j<128;j++) tp += h1[j]*w2[j*64+t];
  }
  red[t] = (t<64)? tp : 0.f;
  __syncthreads();
  for (int st=64;st;st>>=1){ if(t<st) red[t]+=red[t+st]; __syncthreads(); }
  if (t==0) s_mu = red[0]/64.f;
  __syncthreads();
  float d = tp - s_mu;
  red[t] = (t<64)? d*d : 0.f;
  __syncthreads();
  for (int st=64;st;st>>=1){ if(t<st) red[t]+=red[t+st]; __syncthreads(); }
  if (t==0) s_rs = rsqrtf(red[0]/64.f + 1e-5f);
  __syncthreads();
  if (t<64) temb[t] = g[t]*(d*s_rs) + b[t];
}

// ---------------- node encoders: x(in_dim) -> LN128 -> silu -> 48 ----------------
__global__ void k_enc(const float* __restrict__ x, int in_dim,
                      const float* __restrict__ w1, const float* __restrict__ b1,
                      const float* __restrict__ g,  const float* __restrict__ bb,
                      const float* __restrict__ w2, const float* __restrict__ b2,
                      float* __restrict__ out, int row_off){
  __shared__ float sx[96], sh[128], red[128];
  __shared__ float s_mu, s_rs;
  int row = blockIdx.x, t = threadIdx.x;
  for (int i=t;i<in_dim;i+=128) sx[i] = x[(size_t)row*in_dim+i];
  __syncthreads();
  float z = b1[t];
  for (int i=0;i<in_dim;i++) z += sx[i]*w1[i*128+t];
  red[t]=z; __syncthreads();
  for (int st=64;st;st>>=1){ if(t<st) red[t]+=red[t+st]; __syncthreads(); }
  if(!t) s_mu = red[0]/128.f;
  __syncthreads();
  float d = z - s_mu;
  red[t]=d*d; __syncthreads();
  for (int st=64;st;st>>=1){ if(t<st) red[t]+=red[t+st]; __syncthreads(); }
  if(!t) s_rs = rsqrtf(red[0]/128.f+1e-5f);
  __syncthreads();
  float h = g[t]*(d*s_rs)+bb[t];
  sh[t] = silu_f(h);
  __syncthreads();
  if (t<48){
    float o = b2[t];
    for (int j=0;j<128;j++) o += sh[j]*w2[j*48+t];
    out[(size_t)(row_off+row)*48+t] = o;
  }
}

// ---------------- s0 = (enc @ sp_w + sp_b) @ emb_w * I48 ----------------
__global__ void k_s0(const float* __restrict__ enc, const float* __restrict__ spw,
                     const float* __restrict__ spb, const float* __restrict__ embw,
                     float* __restrict__ s){
  __shared__ float se[48], sc[48];
  int n = blockIdx.x, t = threadIdx.x;
  if (t<48) se[t] = enc[(size_t)n*48+t];
  __syncthreads();
  if (t<48){
    float c = spb[t];
    for (int i=0;i<48;i++) c += se[i]*spw[i*48+t];
    sc[t] = c;
  }
  __syncthreads();
  if (t<48){
    float v = 0.f;
    for (int i=0;i<48;i++) v += sc[i]*embw[i*48+t];
    s[(size_t)n*48+t] = v*I48;
  }
}

// ---------------- per-edge: dist -> ef(32); also degree atomics ----------------
__global__ void k_edge(const float* __restrict__ lc, const float* __restrict__ pc,
                       const int* __restrict__ src, const int* __restrict__ dst,
                       const float* __restrict__ temb,
                       const float* __restrict__ w1, const float* __restrict__ b1,
                       const float* __restrict__ w2, const float* __restrict__ b2,
                       float* __restrict__ ef, float* __restrict__ degf,
                       int E, int Nl){
  __shared__ float sh_h[2][32];
  int t = threadIdx.x, sub = t>>5, j = t&31;
  int e = blockIdx.x*2 + sub;
  if (e < E){
    int s_ = src[e], d_ = dst[e];
    float vx = lc[(size_t)s_*3+0]-pc[(size_t)d_*6+0];
    float vy = lc[(size_t)s_*3+1]-pc[(size_t)d_*6+1];
    float vz = lc[(size_t)s_*3+2]-pc[(size_t)d_*6+2];
    float dist = sqrtf(vx*vx+vy*vy+vz*vz+1e-12f);
    float h = b1[j] + dist*w1[j];
    for (int a=0;a<64;a++) h += temb[a]*w1[(a+1)*32+j];
    sh_h[sub][j] = silu_f(h);
  }
  __syncthreads();
  if (e < E){
    float o = b2[j];
    for (int a=0;a<32;a++) o += sh_h[sub][a]*w2[a*32+j];
    ef[(size_t)e*32+j] = o;
    if (j==0) atomicAdd(&degf[Nl + dst[e]], 1.f);
  }
}

// ---------------- per-edge MLP: ef(32) -> 128 -> 128 (silu both) ----------------
__global__ void k_mlp(const float* __restrict__ ef,
                      const float* __restrict__ w1, const float* __restrict__ b1,
                      const float* __restrict__ w2, const float* __restrict__ b2,
                      float* __restrict__ m2){
  __shared__ float sh_e[32], sh_h[128];
  int e = blockIdx.x, t = threadIdx.x;
  if (t<32) sh_e[t] = ef[(size_t)e*32+t];
  __syncthreads();
  float h = b1[t];
  for (int a=0;a<32;a++) h += sh_e[a]*w1[a*128+t];
  sh_h[t] = silu_f(h);
  __syncthreads();
  float h2 = b2[t];
  for (int a=0;a<128;a++) h2 += sh_h[a]*w2[a*128+t];
  m2[(size_t)e*128+t] = silu_f(h2);
}

// ---------------- repack conv_w3 Wss slice into [l][i48][k128][o48] ----------------
__global__ void k_pack(const float* __restrict__ w3, float* __restrict__ wp, int L){
  int total = L*48*128*48;
  for (int idx = blockIdx.x*blockDim.x+threadIdx.x; idx < total; idx += gridDim.x*blockDim.x){
    int o = idx % 48; int r = idx / 48;
    int k = r % 128;  r /= 128;
    int i = r % 48;   int l = r / 48;
    wp[idx] = w3[((size_t)(l*128 + k))*11520 + i*48 + o];
  }
}

// ---------------- THE hot kernel: generate Wss on the fly, contract with se ----------------
#define TE 32
__global__ __launch_bounds__(256) void k_msg(
    const float* __restrict__ m2, const float* __restrict__ s,
    const float* __restrict__ wp,    // layer slice [48][128][48], packed
    const float* __restrict__ b3,    // layer bias, first 2304 entries used
    const int* __restrict__ src, const int* __restrict__ dst,
    float* __restrict__ Sacc, int E, int Nl){
  __shared__ float sh_m2[TE][132];   // +4 pad breaks bank aliasing
  __shared__ float sh_se[TE][48];
  __shared__ float sh_w[128*48];
  __shared__ int   sh_dst[TE];
  int t = threadIdx.x;
  int e0 = blockIdx.x*TE;
  for (int q = t; q < TE*32; q += 256){
    int e = q >> 5, c = q & 31;
    float4 v4 = make_float4(0.f,0.f,0.f,0.f);
    if (e0+e < E) v4 = ((const float4*)m2)[(size_t)(e0+e)*32 + c];
    *(float4*)&sh_m2[e][c*4] = v4;
  }
  for (int q = t; q < TE*48; q += 256){
    int e = q / 48, i = q % 48;
    sh_se[e][i] = (e0+e < E) ? s[(size_t)src[e0+e]*48 + i] : 0.f;
  }
  if (t < TE) sh_dst[t] = (e0+t < E) ? (Nl + dst[e0+t]) : 0;
  int eloc = t >> 3;
  int og = (t & 7)*6;
  float ms[6] = {0,0,0,0,0,0};
  for (int i=0;i<48;i++){
    __syncthreads();
    const float4* srcw = (const float4*)(wp + (size_t)i*6144);
    float4* dstw = (float4*)sh_w;
    for (int q=t; q<1536; q+=256) dstw[q] = srcw[q];
    __syncthreads();
    float acc[6] = {0,0,0,0,0,0};
    const float* wr = sh_w + og;
    const float* mr = sh_m2[eloc];
    #pragma unroll 4
    for (int k=0;k<128;k++){
      float mk = mr[k];
      const float* w_ = wr + k*48;
      acc[0] += mk*w_[0]; acc[1] += mk*w_[1]; acc[2] += mk*w_[2];
      acc[3] += mk*w_[3]; acc[4] += mk*w_[4]; acc[5] += mk*w_[5];
    }
    float se_i = sh_se[eloc][i];
    const float* bb = b3 + i*48 + og;
    #pragma unroll
    for (int j=0;j<6;j++) ms[j] += se_i*(acc[j] + bb[j]);
  }
  if (e0 + eloc < E){
    int nd = sh_dst[eloc];
    #pragma unroll
    for (int j=0;j<6;j++) atomicAdd(&Sacc[(size_t)nd*48 + og + j], ms[j]*I48);
  }
}

// ---------------- node update: a_s = Sacc/deg + s@si_ws*I48 ; BN partial sums ----------------
__global__ void k_node(const float* __restrict__ Sacc, const float* __restrict__ degf,
                       const float* __restrict__ s, const float* __restrict__ siw,
                       float* __restrict__ a_s, float* __restrict__ bnsum, float* __restrict__ bnsq,
                       int N){
  __shared__ float sh_s[16][48];
  __shared__ float csum[48], csq[48];
  int t = threadIdx.x;
  int n0 = blockIdx.x*16;
  if (t<48){ csum[t]=0.f; csq[t]=0.f; }
  for (int q=t;q<16*48;q+=256){
    int nl=q/48, i=q%48;
    sh_s[nl][i] = s[(size_t)(n0+nl)*48+i];
  }
  __syncthreads();
  int nl = t>>4;
  int ob = (t&15)*3;
  int n = n0+nl;
  float dg = degf[n]; if (dg < 1.f) dg = 1.f;
  float inv = 1.f/dg;
  #pragma unroll
  for (int j=0;j<3;j++){
    int o = ob+j;
    float a = Sacc[(size_t)n*48+o]*inv;
    float acc = 0.f;
    for (int i=0;i<48;i++) acc += sh_s[nl][i]*siw[i*48+o];
    a += acc*I48;
    a_s[(size_t)n*48+o] = a;
    atomicAdd(&csum[o], a);
    atomicAdd(&csq[o], a*a);
  }
  __syncthreads();
  if (t<48){ atomicAdd(&bnsum[t], csum[t]); atomicAdd(&bnsq[t], csq[t]); }
}

__global__ void k_bnfin(const float* __restrict__ bnsum, const float* __restrict__ bnsq,
                        const float* __restrict__ g, const float* __restrict__ b,
                        float* __restrict__ kscale, float* __restrict__ kbias, int N){
  int t = threadIdx.x;
  if (t<48){
    float mu  = bnsum[t]/(float)N;
    float var = bnsq[t]/(float)N - mu*mu;
    float r = rsqrtf(var + 1e-5f);
    float sc = g[t]*r;
    kscale[t] = sc;
    kbias[t]  = b[t] - mu*sc;
  }
}

__global__ void k_supd(float* __restrict__ s, const float* __restrict__ a_s,
                       const float* __restrict__ kscale, const float* __restrict__ kbias, int total){
  int idx = blockIdx.x*blockDim.x+threadIdx.x;
  if (idx < total){
    int o = idx % 48;
    s[idx] += a_s[idx]*kscale[o] + kbias[o];
  }
}

// ---------------- output: [vf(=0,3), s@out_ws*I48 (256)] per ligand node ----------------
__global__ void k_out(const float* __restrict__ s, const float* __restrict__ ows,
                      float* __restrict__ out){
  __shared__ float sh_s[48];
  int n = blockIdx.x, t = threadIdx.x;
  if (t<48) sh_s[t] = s[(size_t)n*48+t];
  __syncthreads();
  float acc = 0.f;
  for (int i=0;i<48;i++) acc += sh_s[i]*ows[i*256+t];
  out[(size_t)n*259 + 3 + t] = acc*I48;
  if (t<3) out[(size_t)n*259 + t] = 0.f;
}

extern "C" void kernel_launch(void* const* d_in, const int* in_sizes, int n_in,
                              void* d_out, int out_size, void* d_ws, size_t ws_size,
                              hipStream_t stream){
  const float* protein_coords   = (const float*)d_in[0];
  const float* protein_features = (const float*)d_in[1];
  const float* ligand_coords    = (const float*)d_in[2];
  const float* ligand_features  = (const float*)d_in[3];
  const float* t_in    = (const float*)d_in[4];
  const float* te_w1   = (const float*)d_in[5];
  const float* te_b1   = (const float*)d_in[6];
  const float* te_w2   = (const float*)d_in[7];
  const float* te_b2   = (const float*)d_in[8];
  const float* te_ln_g = (const float*)d_in[9];
  const float* te_ln_b = (const float*)d_in[10];
  const float* pe_w1   = (const float*)d_in[11];
  const float* pe_b1   = (const float*)d_in[12];
  const float* pe_ln_g = (const float*)d_in[13];
  const float* pe_ln_b = (const float*)d_in[14];
  const float* pe_w2   = (const float*)d_in[15];
  const float* pe_b2   = (const float*)d_in[16];
  const float* le_w1   = (const float*)d_in[17];
  const float* le_b1   = (const float*)d_in[18];
  const float* le_ln_g = (const float*)d_in[19];
  const float* le_ln_b = (const float*)d_in[20];
  const float* le_w2   = (const float*)d_in[21];
  const float* le_b2   = (const float*)d_in[22];
  const float* sp_w    = (const float*)d_in[23];
  const float* sp_b    = (const float*)d_in[24];
  const float* emb_w   = (const float*)d_in[25];
  const float* ee_w1   = (const float*)d_in[26];
  const float* ee_b1   = (const float*)d_in[27];
  const float* ee_w2   = (const float*)d_in[28];
  const float* ee_b2   = (const float*)d_in[29];
  const float* conv_w1 = (const float*)d_in[30];
  const float* conv_b1 = (const float*)d_in[31];
  const float* conv_w2 = (const float*)d_in[32];
  const float* conv_b2 = (const float*)d_in[33];
  const float* conv_w3 = (const float*)d_in[34];
  const float* conv_b3 = (const float*)d_in[35];
  const float* bn_gs   = (const float*)d_in[36];
  const float* bn_bs   = (const float*)d_in[37];
  const float* si_ws   = (const float*)d_in[40];
  const float* out_ws  = (const float*)d_in[43];
  const int* edge_src  = (const int*)d_in[45];
  const int* edge_dst  = (const int*)d_in[46];

  int Np = in_sizes[0]/6;
  int Nl = in_sizes[2]/3;
  int E  = in_sizes[45];
  int N  = Nl+Np;
  int L  = in_sizes[36]/48;

  float* W = (float*)d_ws;
  size_t off = 0;
  auto alloc = [&](size_t n)->float*{ float* p = W+off; off += (n+63)&~(size_t)63; return p; };
  float* temb  = alloc(64);
  float* enc   = alloc((size_t)N*48);
  float* sbuf  = alloc((size_t)N*48);
  float* ef    = alloc((size_t)E*32);
  float* m2    = alloc((size_t)E*128);
  float* degf  = alloc(N);
  float* Sacc  = alloc((size_t)N*48);   // Sacc, bnsum, bnsq contiguous -> one memset
  float* bnsum = alloc(64);
  float* bnsq  = alloc(64);
  float* a_s   = alloc((size_t)N*48);
  float* kscale= alloc(64);
  float* kbias = alloc(64);
  float* wp    = alloc((size_t)L*48*128*48);

  hipMemsetAsync(degf, 0, (size_t)N*sizeof(float), stream);
  k_pack<<<512,256,0,stream>>>(conv_w3, wp, L);
  k_temb<<<1,128,0,stream>>>(t_in, te_w1, te_b1, te_w2, te_b2, te_ln_g, te_ln_b, temb);
  k_enc<<<Np,128,0,stream>>>(protein_features, 96, pe_w1, pe_b1, pe_ln_g, pe_ln_b, pe_w2, pe_b2, enc, Nl);
  k_enc<<<Nl,128,0,stream>>>(ligand_features, 52, le_w1, le_b1, le_ln_g, le_ln_b, le_w2, le_b2, enc, 0);
  k_s0<<<N,64,0,stream>>>(enc, sp_w, sp_b, emb_w, sbuf);
  k_edge<<<(E+1)/2,64,0,stream>>>(ligand_coords, protein_coords, edge_src, edge_dst, temb,
                                  ee_w1, ee_b1, ee_w2, ee_b2, ef, degf, E, Nl);
  for (int l=0;l<L;l++){
    hipMemsetAsync(Sacc, 0, ((size_t)N*48 + 128)*sizeof(float), stream);
    k_mlp<<<E,128,0,stream>>>(ef, conv_w1 + (size_t)l*32*128, conv_b1 + (size_t)l*128,
                              conv_w2 + (size_t)l*128*128, conv_b2 + (size_t)l*128, m2);
    k_msg<<<(E+TE-1)/TE,256,0,stream>>>(m2, sbuf, wp + (size_t)l*48*128*48,
                                        conv_b3 + (size_t)l*11520,
                                        edge_src, edge_dst, Sacc, E, Nl);
    k_node<<<N/16,256,0,stream>>>(Sacc, degf, sbuf, si_ws + (size_t)l*2304, a_s, bnsum, bnsq, N);
    k_bnfin<<<1,64,0,stream>>>(bnsum, bnsq, bn_gs + l*48, bn_bs + l*48, kscale, kbias, N);
    k_supd<<<((size_t)N*48+255)/256,256,0,stream>>>(sbuf, a_s, kscale, kbias, N*48);
  }
  k_out<<<Nl,256,0,stream>>>(sbuf, out_ws, (float*)d_out);
}

// Round 2
// 943.897 us; speedup vs baseline: 2.3529x; 2.3529x over previous
//
#include <hip/hip_runtime.h>
#include <hip/hip_bf16.h>
#include <math.h>

#define I48 0.14433756729740643f  // 1/sqrt(48)

typedef __attribute__((ext_vector_type(8))) short short8;
typedef __attribute__((ext_vector_type(4))) float f32x4;

__device__ __forceinline__ float silu_f(float x){ return x / (1.f + __expf(-x)); }

__device__ __forceinline__ unsigned short f2bf(float f){
  unsigned u = __builtin_bit_cast(unsigned, f);
  unsigned r = (u + 0x7fff + ((u >> 16) & 1)) >> 16;   // RNE, finite inputs
  return (unsigned short)r;
}

// ---------------- time embedding (1 block, 128 thr) ----------------
__global__ void k_temb(const float* __restrict__ t_in,
                       const float* __restrict__ w1, const float* __restrict__ b1,
                       const float* __restrict__ w2, const float* __restrict__ b2,
                       const float* __restrict__ g,  const float* __restrict__ b,
                       float* __restrict__ temb){
  __shared__ float emb[64], h1[128], red[128];
  __shared__ float s_mu, s_rs;
  int t = threadIdx.x;
  float tv = t_in[0];
  if (t < 64){
    int i = t & 31;
    float fr = __expf((float)i * (-9.210340371976184f/31.f));
    float a = tv * fr;
    emb[t] = (t < 32) ? sinf(a) : cosf(a);
  }
  __syncthreads();
  {
    float z = b1[t];
    for (int i=0;i<64;i++) z += emb[i]*w1[i*128+t];
    h1[t] = silu_f(z);
  }
  __syncthreads();
  float tp = 0.f;
  if (t < 64){
    tp = b2[t];
    for (int j=0;j<128;j++) tp += h1[j]*w2[j*64+t];
  }
  red[t] = (t<64)? tp : 0.f;
  __syncthreads();
  for (int st=64;st;st>>=1){ if(t<st) red[t]+=red[t+st]; __syncthreads(); }
  if (t==0) s_mu = red[0]/64.f;
  __syncthreads();
  float d = tp - s_mu;
  red[t] = (t<64)? d*d : 0.f;
  __syncthreads();
  for (int st=64;st;st>>=1){ if(t<st) red[t]+=red[t+st]; __syncthreads(); }
  if (t==0) s_rs = rsqrtf(red[0]/64.f + 1e-5f);
  __syncthreads();
  if (t<64) temb[t] = g[t]*(d*s_rs) + b[t];
}

// ---------------- node encoders: x(in_dim) -> LN128 -> silu -> 48 ----------------
__global__ void k_enc(const float* __restrict__ x, int in_dim,
                      const float* __restrict__ w1, const float* __restrict__ b1,
                      const float* __restrict__ g,  const float* __restrict__ bb,
                      const float* __restrict__ w2, const float* __restrict__ b2,
                      float* __restrict__ out, int row_off){
  __shared__ float sx[96], sh[128], red[128];
  __shared__ float s_mu, s_rs;
  int row = blockIdx.x, t = threadIdx.x;
  for (int i=t;i<in_dim;i+=128) sx[i] = x[(size_t)row*in_dim+i];
  __syncthreads();
  float z = b1[t];
  for (int i=0;i<in_dim;i++) z += sx[i]*w1[i*128+t];
  red[t]=z; __syncthreads();
  for (int st=64;st;st>>=1){ if(t<st) red[t]+=red[t+st]; __syncthreads(); }
  if(!t) s_mu = red[0]/128.f;
  __syncthreads();
  float d = z - s_mu;
  red[t]=d*d; __syncthreads();
  for (int st=64;st;st>>=1){ if(t<st) red[t]+=red[t+st]; __syncthreads(); }
  if(!t) s_rs = rsqrtf(red[0]/128.f+1e-5f);
  __syncthreads();
  float h = g[t]*(d*s_rs)+bb[t];
  sh[t] = silu_f(h);
  __syncthreads();
  if (t<48){
    float o = b2[t];
    for (int j=0;j<128;j++) o += sh[j]*w2[j*48+t];
    out[(size_t)(row_off+row)*48+t] = o;
  }
}

// ---------------- s0 = (enc @ sp_w + sp_b) @ emb_w * I48 ----------------
__global__ void k_s0(const float* __restrict__ enc, const float* __restrict__ spw,
                     const float* __restrict__ spb, const float* __restrict__ embw,
                     float* __restrict__ s){
  __shared__ float se[48], sc[48];
  int n = blockIdx.x, t = threadIdx.x;
  if (t<48) se[t] = enc[(size_t)n*48+t];
  __syncthreads();
  if (t<48){
    float c = spb[t];
    for (int i=0;i<48;i++) c += se[i]*spw[i*48+t];
    sc[t] = c;
  }
  __syncthreads();
  if (t<48){
    float v = 0.f;
    for (int i=0;i<48;i++) v += sc[i]*embw[i*48+t];
    s[(size_t)n*48+t] = v*I48;
  }
}

// ---------------- per-edge: dist -> ef(32); also degree atomics ----------------
__global__ void k_edge(const float* __restrict__ lc, const float* __restrict__ pc,
                       const int* __restrict__ src, const int* __restrict__ dst,
                       const float* __restrict__ temb,
                       const float* __restrict__ w1, const float* __restrict__ b1,
                       const float* __restrict__ w2, const float* __restrict__ b2,
                       float* __restrict__ ef, float* __restrict__ degf,
                       int E, int Nl){
  __shared__ float sh_h[2][32];
  int t = threadIdx.x, sub = t>>5, j = t&31;
  int e = blockIdx.x*2 + sub;
  if (e < E){
    int s_ = src[e], d_ = dst[e];
    float vx = lc[(size_t)s_*3+0]-pc[(size_t)d_*6+0];
    float vy = lc[(size_t)s_*3+1]-pc[(size_t)d_*6+1];
    float vz = lc[(size_t)s_*3+2]-pc[(size_t)d_*6+2];
    float dist = sqrtf(vx*vx+vy*vy+vz*vz+1e-12f);
    float h = b1[j] + dist*w1[j];
    for (int a=0;a<64;a++) h += temb[a]*w1[(a+1)*32+j];
    sh_h[sub][j] = silu_f(h);
  }
  __syncthreads();
  if (e < E){
    float o = b2[j];
    for (int a=0;a<32;a++) o += sh_h[sub][a]*w2[a*32+j];
    ef[(size_t)e*32+j] = o;
    if (j==0) atomicAdd(&degf[Nl + dst[e]], 1.f);
  }
}

// ---------------- per-edge MLP: ef(32) -> 128 -> 128 (silu both) ----------------
__global__ void k_mlp(const float* __restrict__ ef,
                      const float* __restrict__ w1, const float* __restrict__ b1,
                      const float* __restrict__ w2, const float* __restrict__ b2,
                      float* __restrict__ m2){
  __shared__ float sh_e[32], sh_h[128];
  int e = blockIdx.x, t = threadIdx.x;
  if (t<32) sh_e[t] = ef[(size_t)e*32+t];
  __syncthreads();
  float h = b1[t];
  for (int a=0;a<32;a++) h += sh_e[a]*w1[a*128+t];
  sh_h[t] = silu_f(h);
  __syncthreads();
  float h2 = b2[t];
  for (int a=0;a<128;a++) h2 += sh_h[a]*w2[a*128+t];
  m2[(size_t)e*128+t] = silu_f(h2);
}

// ---------------- pack W (+bias rows) into MFMA B-fragment order, bf16 ----------------
// Layout: idx = ((((l*194 + kblk)*3 + nt)*64 + lane)*8 + j)
// value:  kp = kblk*32 + (lane>>4)*8 + j; o = nt*16 + (lane&15)
//   kp<6144 : W[i= kp>>7][kk= kp&127][o] = w3[(l*128+kk)*11520 + i*48 + o]
//   else    : ii = kp-6144; ii<48 ? b3[l*11520 + ii*48 + o] : 0
#define NKB 194
__global__ void k_packB(const float* __restrict__ w3, const float* __restrict__ b3,
                        unsigned short* __restrict__ wb, int L){
  int total = L*NKB*1536;
  for (int idx = blockIdx.x*blockDim.x+threadIdx.x; idx < total; idx += gridDim.x*blockDim.x){
    int j = idx & 7;
    int lane = (idx >> 3) & 63;
    int rest = idx >> 9;
    int nt = rest % 3; int rest2 = rest / 3;
    int kblk = rest2 % NKB; int l = rest2 / NKB;
    int kp = kblk*32 + ((lane>>4)<<3) + j;
    int o  = nt*16 + (lane & 15);
    float v;
    if (kp < 6144){
      int i = kp >> 7, kk = kp & 127;
      v = w3[((size_t)(l*128 + kk))*11520 + i*48 + o];
    } else {
      int ii = kp - 6144;
      v = (ii < 48) ? b3[(size_t)l*11520 + ii*48 + o] : 0.f;
    }
    wb[idx] = f2bf(v);
  }
}

// ---------------- hot kernel: on-the-fly Z = se⊗m2 (bf16), MFMA GEMM vs packed W ----------------
#define KCH 8   // kblks per LDS chunk (24 KiB)
__global__ __launch_bounds__(128) void k_msg2(
    const float* __restrict__ m2g, const float* __restrict__ s,
    const unsigned short* __restrict__ wb,   // layer base, packed B
    const int* __restrict__ src, const int* __restrict__ dst,
    float* __restrict__ Sacc, int Nl){
  __shared__ __align__(16) unsigned short sB[2][KCH*1536];  // 2 x 24 KiB
  __shared__ __align__(16) float sm2[32][132];              // +4 pad: 2-way max
  __shared__ float sse[32][49];                             // +1 pad: conflict-free
  __shared__ int sdst[32];
  const int t = threadIdx.x, lane = t & 63, w = t >> 6;
  const int e0 = blockIdx.x * 32;

  for (int q = t; q < 32*32; q += 128){
    int e = q >> 5, c = q & 31;
    float4 v = ((const float4*)m2g)[(size_t)(e0+e)*32 + c];
    *(float4*)&sm2[e][c*4] = v;
  }
  for (int q = t; q < 32*48; q += 128){
    int e = q / 48, i = q - e*48;
    sse[e][i] = s[(size_t)src[e0+e]*48 + i];
  }
  if (t < 32) sdst[t] = dst[e0+t];

  auto stage = [&](int c){
    int kb0 = c*KCH;
    int nk = NKB - kb0; if (nk > KCH) nk = KCH;
    int bytes = nk*3072;
    const char* g = (const char*)wb + (size_t)kb0*3072;
    char* lb = (char*)sB[c&1];
    for (int off = w*1024; off < bytes; off += 2048){
      __builtin_amdgcn_global_load_lds(
        (const __attribute__((address_space(1))) void*)(g + off + (size_t)lane*16),
        (__attribute__((address_space(3))) void*)(lb + off), 16, 0, 0);
    }
  };
  stage(0);

  f32x4 acc0 = {0.f,0.f,0.f,0.f}, acc1 = {0.f,0.f,0.f,0.f}, acc2 = {0.f,0.f,0.f,0.f};
  const int m = lane & 15, quad = lane >> 4;
  const int eL = w*16 + m;
  const int nch = (NKB + KCH - 1)/KCH;  // 25
  for (int c = 0; c < nch; c++){
    __syncthreads();              // implicit vmcnt(0) drain: chunk c resident
    if (c+1 < nch) stage(c+1);    // overlaps compute(c)
    int kb0 = c*KCH;
    int kbn = NKB - kb0; if (kbn > KCH) kbn = KCH;
    const unsigned short* bb = sB[c&1];
    for (int kk = 0; kk < kbn; kk++){
      int kblk = kb0 + kk;
      short8 a;
      if (kblk < 192){
        int i = kblk >> 2;
        int base = ((kblk & 3) << 5) + quad*8;
        float sv = sse[eL][i];
        float4 p0 = *(const float4*)&sm2[eL][base];
        float4 p1 = *(const float4*)&sm2[eL][base+4];
        a[0]=(short)f2bf(sv*p0.x); a[1]=(short)f2bf(sv*p0.y);
        a[2]=(short)f2bf(sv*p0.z); a[3]=(short)f2bf(sv*p0.w);
        a[4]=(short)f2bf(sv*p1.x); a[5]=(short)f2bf(sv*p1.y);
        a[6]=(short)f2bf(sv*p1.z); a[7]=(short)f2bf(sv*p1.w);
      } else {
        int ib = ((kblk-192) << 5) + quad*8;
        #pragma unroll
        for (int j=0;j<8;j++){
          int ii = ib + j;
          float sv2 = (ii < 48) ? sse[eL][ii] : 0.f;
          a[j] = (short)f2bf(sv2);
        }
      }
      const unsigned short* bk = bb + kk*1536 + lane*8;
      short8 b0 = *(const short8*)(bk);
      short8 b1 = *(const short8*)(bk + 512);
      short8 b2 = *(const short8*)(bk + 1024);
      acc0 = __builtin_amdgcn_mfma_f32_16x16x32_bf16(a, b0, acc0, 0, 0, 0);
      acc1 = __builtin_amdgcn_mfma_f32_16x16x32_bf16(a, b1, acc1, 0, 0, 0);
      acc2 = __builtin_amdgcn_mfma_f32_16x16x32_bf16(a, b2, acc2, 0, 0, 0);
    }
  }
  // epilogue: D[row = quad*4+r][col = m], o = nt*16 + m
  #pragma unroll
  for (int r = 0; r < 4; r++){
    int el = w*16 + quad*4 + r;
    int nd = Nl + sdst[el];
    float* rowp = Sacc + (size_t)nd*48 + m;
    atomicAdd(rowp +  0, acc0[r]*I48);
    atomicAdd(rowp + 16, acc1[r]*I48);
    atomicAdd(rowp + 32, acc2[r]*I48);
  }
}

// ---------------- node update: a_s = Sacc/deg + s@si_ws*I48 ; BN partial sums ----------------
__global__ void k_node(const float* __restrict__ Sacc, const float* __restrict__ degf,
                       const float* __restrict__ s, const float* __restrict__ siw,
                       float* __restrict__ a_s, float* __restrict__ bnsum, float* __restrict__ bnsq,
                       int N){
  __shared__ float sh_s[16][48];
  __shared__ float csum[48], csq[48];
  int t = threadIdx.x;
  int n0 = blockIdx.x*16;
  if (t<48){ csum[t]=0.f; csq[t]=0.f; }
  for (int q=t;q<16*48;q+=256){
    int nl=q/48, i=q%48;
    sh_s[nl][i] = s[(size_t)(n0+nl)*48+i];
  }
  __syncthreads();
  int nl = t>>4;
  int ob = (t&15)*3;
  int n = n0+nl;
  float dg = degf[n]; if (dg < 1.f) dg = 1.f;
  float inv = 1.f/dg;
  #pragma unroll
  for (int j=0;j<3;j++){
    int o = ob+j;
    float a = Sacc[(size_t)n*48+o]*inv;
    float acc = 0.f;
    for (int i=0;i<48;i++) acc += sh_s[nl][i]*siw[i*48+o];
    a += acc*I48;
    a_s[(size_t)n*48+o] = a;
    atomicAdd(&csum[o], a);
    atomicAdd(&csq[o], a*a);
  }
  __syncthreads();
  if (t<48){ atomicAdd(&bnsum[t], csum[t]); atomicAdd(&bnsq[t], csq[t]); }
}

__global__ void k_bnfin(const float* __restrict__ bnsum, const float* __restrict__ bnsq,
                        const float* __restrict__ g, const float* __restrict__ b,
                        float* __restrict__ kscale, float* __restrict__ kbias, int N){
  int t = threadIdx.x;
  if (t<48){
    float mu  = bnsum[t]/(float)N;
    float var = bnsq[t]/(float)N - mu*mu;
    float r = rsqrtf(var + 1e-5f);
    float sc = g[t]*r;
    kscale[t] = sc;
    kbias[t]  = b[t] - mu*sc;
  }
}

__global__ void k_supd(float* __restrict__ s, const float* __restrict__ a_s,
                       const float* __restrict__ kscale, const float* __restrict__ kbias, int total){
  int idx = blockIdx.x*blockDim.x+threadIdx.x;
  if (idx < total){
    int o = idx % 48;
    s[idx] += a_s[idx]*kscale[o] + kbias[o];
  }
}

// ---------------- output: [vf(=0,3), s@out_ws*I48 (256)] per ligand node ----------------
__global__ void k_out(const float* __restrict__ s, const float* __restrict__ ows,
                      float* __restrict__ out){
  __shared__ float sh_s[48];
  int n = blockIdx.x, t = threadIdx.x;
  if (t<48) sh_s[t] = s[(size_t)n*48+t];
  __syncthreads();
  float acc = 0.f;
  for (int i=0;i<48;i++) acc += sh_s[i]*ows[i*256+t];
  out[(size_t)n*259 + 3 + t] = acc*I48;
  if (t<3) out[(size_t)n*259 + t] = 0.f;
}

extern "C" void kernel_launch(void* const* d_in, const int* in_sizes, int n_in,
                              void* d_out, int out_size, void* d_ws, size_t ws_size,
                              hipStream_t stream){
  const float* protein_coords   = (const float*)d_in[0];
  const float* protein_features = (const float*)d_in[1];
  const float* ligand_coords    = (const float*)d_in[2];
  const float* ligand_features  = (const float*)d_in[3];
  const float* t_in    = (const float*)d_in[4];
  const float* te_w1   = (const float*)d_in[5];
  const float* te_b1   = (const float*)d_in[6];
  const float* te_w2   = (const float*)d_in[7];
  const float* te_b2   = (const float*)d_in[8];
  const float* te_ln_g = (const float*)d_in[9];
  const float* te_ln_b = (const float*)d_in[10];
  const float* pe_w1   = (const float*)d_in[11];
  const float* pe_b1   = (const float*)d_in[12];
  const float* pe_ln_g = (const float*)d_in[13];
  const float* pe_ln_b = (const float*)d_in[14];
  const float* pe_w2   = (const float*)d_in[15];
  const float* pe_b2   = (const float*)d_in[16];
  const float* le_w1   = (const float*)d_in[17];
  const float* le_b1   = (const float*)d_in[18];
  const float* le_ln_g = (const float*)d_in[19];
  const float* le_ln_b = (const float*)d_in[20];
  const float* le_w2   = (const float*)d_in[21];
  const float* le_b2   = (const float*)d_in[22];
  const float* sp_w    = (const float*)d_in[23];
  const float* sp_b    = (const float*)d_in[24];
  const float* emb_w   = (const float*)d_in[25];
  const float* ee_w1   = (const float*)d_in[26];
  const float* ee_b1   = (const float*)d_in[27];
  const float* ee_w2   = (const float*)d_in[28];
  const float* ee_b2   = (const float*)d_in[29];
  const float* conv_w1 = (const float*)d_in[30];
  const float* conv_b1 = (const float*)d_in[31];
  const float* conv_w2 = (const float*)d_in[32];
  const float* conv_b2 = (const float*)d_in[33];
  const float* conv_w3 = (const float*)d_in[34];
  const float* conv_b3 = (const float*)d_in[35];
  const float* bn_gs   = (const float*)d_in[36];
  const float* bn_bs   = (const float*)d_in[37];
  const float* si_ws   = (const float*)d_in[40];
  const float* out_ws  = (const float*)d_in[43];
  const int* edge_src  = (const int*)d_in[45];
  const int* edge_dst  = (const int*)d_in[46];

  int Np = in_sizes[0]/6;
  int Nl = in_sizes[2]/3;
  int E  = in_sizes[45];
  int N  = Nl+Np;
  int L  = in_sizes[36]/48;

  float* W = (float*)d_ws;
  size_t off = 0;
  auto alloc = [&](size_t n)->float*{ float* p = W+off; off += (n+63)&~(size_t)63; return p; };
  float* temb  = alloc(64);
  float* enc   = alloc((size_t)N*48);
  float* sbuf  = alloc((size_t)N*48);
  float* ef    = alloc((size_t)E*32);
  float* m2    = alloc((size_t)E*128);
  float* degf  = alloc(N);
  float* Sacc  = alloc((size_t)N*48);
  float* bnsum = alloc(64);
  float* bnsq  = alloc(64);
  float* a_s   = alloc((size_t)N*48);
  float* kscale= alloc(64);
  float* kbias = alloc(64);
  unsigned short* wb = (unsigned short*)alloc((size_t)L*NKB*1536/2 + 64);

  hipMemsetAsync(degf, 0, (size_t)N*sizeof(float), stream);
  k_packB<<<896,256,0,stream>>>(conv_w3, conv_b3, wb, L);
  k_temb<<<1,128,0,stream>>>(t_in, te_w1, te_b1, te_w2, te_b2, te_ln_g, te_ln_b, temb);
  k_enc<<<Np,128,0,stream>>>(protein_features, 96, pe_w1, pe_b1, pe_ln_g, pe_ln_b, pe_w2, pe_b2, enc, Nl);
  k_enc<<<Nl,128,0,stream>>>(ligand_features, 52, le_w1, le_b1, le_ln_g, le_ln_b, le_w2, le_b2, enc, 0);
  k_s0<<<N,64,0,stream>>>(enc, sp_w, sp_b, emb_w, sbuf);
  k_edge<<<(E+1)/2,64,0,stream>>>(ligand_coords, protein_coords, edge_src, edge_dst, temb,
                                  ee_w1, ee_b1, ee_w2, ee_b2, ef, degf, E, Nl);
  for (int l=0;l<L;l++){
    hipMemsetAsync(Sacc, 0, ((size_t)N*48 + 128)*sizeof(float), stream);
    k_mlp<<<E,128,0,stream>>>(ef, conv_w1 + (size_t)l*32*128, conv_b1 + (size_t)l*128,
                              conv_w2 + (size_t)l*128*128, conv_b2 + (size_t)l*128, m2);
    k_msg2<<<E/32,128,0,stream>>>(m2, sbuf, wb + (size_t)l*NKB*1536,
                                  edge_src, edge_dst, Sacc, Nl);
    k_node<<<N/16,256,0,stream>>>(Sacc, degf, sbuf, si_ws + (size_t)l*2304, a_s, bnsum, bnsq, N);
    k_bnfin<<<1,64,0,stream>>>(bnsum, bnsq, bn_gs + l*48, bn_bs + l*48, kscale, kbias, N);
    k_supd<<<((size_t)N*48+255)/256,256,0,stream>>>(sbuf, a_s, kscale, kbias, N*48);
  }
  k_out<<<Nl,256,0,stream>>>(sbuf, out_ws, (float*)d_out);
}

// Round 3
// 651.728 us; speedup vs baseline: 3.4078x; 1.4483x over previous
//
#include <hip/hip_runtime.h>
#include <hip/hip_bf16.h>
#include <math.h>

#define I48 0.14433756729740643f  // 1/sqrt(48)
#define NKB 194                   // 6144 W rows + 64 bias rows, /32
#define KCH 4                     // kblks per LDS chunk (12 KiB fp16)
#define KSPL 6                    // K-split across blockIdx.y

typedef __attribute__((ext_vector_type(8))) _Float16 half8;
typedef __attribute__((ext_vector_type(4))) float f32x4;

__device__ __forceinline__ float silu_f(float x){ return x / (1.f + __expf(-x)); }

// ---------------- time embedding (1 block, 128 thr) ----------------
__global__ void k_temb(const float* __restrict__ t_in,
                       const float* __restrict__ w1, const float* __restrict__ b1,
                       const float* __restrict__ w2, const float* __restrict__ b2,
                       const float* __restrict__ g,  const float* __restrict__ b,
                       float* __restrict__ temb){
  __shared__ float emb[64], h1[128], red[128];
  __shared__ float s_mu, s_rs;
  int t = threadIdx.x;
  float tv = t_in[0];
  if (t < 64){
    int i = t & 31;
    float fr = __expf((float)i * (-9.210340371976184f/31.f));
    float a = tv * fr;
    emb[t] = (t < 32) ? sinf(a) : cosf(a);
  }
  __syncthreads();
  {
    float z = b1[t];
    for (int i=0;i<64;i++) z += emb[i]*w1[i*128+t];
    h1[t] = silu_f(z);
  }
  __syncthreads();
  float tp = 0.f;
  if (t < 64){
    tp = b2[t];
    for (int j=0;j<128;j++) tp += h1[j]*w2[j*64+t];
  }
  red[t] = (t<64)? tp : 0.f;
  __syncthreads();
  for (int st=64;st;st>>=1){ if(t<st) red[t]+=red[t+st]; __syncthreads(); }
  if (t==0) s_mu = red[0]/64.f;
  __syncthreads();
  float d = tp - s_mu;
  red[t] = (t<64)? d*d : 0.f;
  __syncthreads();
  for (int st=64;st;st>>=1){ if(t<st) red[t]+=red[t+st]; __syncthreads(); }
  if (t==0) s_rs = rsqrtf(red[0]/64.f + 1e-5f);
  __syncthreads();
  if (t<64) temb[t] = g[t]*(d*s_rs) + b[t];
}

// ---------------- node encoders: x(in_dim) -> LN128 -> silu -> 48 ----------------
__global__ void k_enc(const float* __restrict__ x, int in_dim,
                      const float* __restrict__ w1, const float* __restrict__ b1,
                      const float* __restrict__ g,  const float* __restrict__ bb,
                      const float* __restrict__ w2, const float* __restrict__ b2,
                      float* __restrict__ out, int row_off){
  __shared__ float sx[96], sh[128], red[128];
  __shared__ float s_mu, s_rs;
  int row = blockIdx.x, t = threadIdx.x;
  for (int i=t;i<in_dim;i+=128) sx[i] = x[(size_t)row*in_dim+i];
  __syncthreads();
  float z = b1[t];
  for (int i=0;i<in_dim;i++) z += sx[i]*w1[i*128+t];
  red[t]=z; __syncthreads();
  for (int st=64;st;st>>=1){ if(t<st) red[t]+=red[t+st]; __syncthreads(); }
  if(!t) s_mu = red[0]/128.f;
  __syncthreads();
  float d = z - s_mu;
  red[t]=d*d; __syncthreads();
  for (int st=64;st;st>>=1){ if(t<st) red[t]+=red[t+st]; __syncthreads(); }
  if(!t) s_rs = rsqrtf(red[0]/128.f+1e-5f);
  __syncthreads();
  float h = g[t]*(d*s_rs)+bb[t];
  sh[t] = silu_f(h);
  __syncthreads();
  if (t<48){
    float o = b2[t];
    for (int j=0;j<128;j++) o += sh[j]*w2[j*48+t];
    out[(size_t)(row_off+row)*48+t] = o;
  }
}

// ---------------- s0 = (enc @ sp_w + sp_b) @ emb_w * I48 ----------------
__global__ void k_s0(const float* __restrict__ enc, const float* __restrict__ spw,
                     const float* __restrict__ spb, const float* __restrict__ embw,
                     float* __restrict__ s){
  __shared__ float se[48], sc[48];
  int n = blockIdx.x, t = threadIdx.x;
  if (t<48) se[t] = enc[(size_t)n*48+t];
  __syncthreads();
  if (t<48){
    float c = spb[t];
    for (int i=0;i<48;i++) c += se[i]*spw[i*48+t];
    sc[t] = c;
  }
  __syncthreads();
  if (t<48){
    float v = 0.f;
    for (int i=0;i<48;i++) v += sc[i]*embw[i*48+t];
    s[(size_t)n*48+t] = v*I48;
  }
}

// ---------------- per-edge: dist -> ef(32); also degree atomics ----------------
__global__ void k_edge(const float* __restrict__ lc, const float* __restrict__ pc,
                       const int* __restrict__ src, const int* __restrict__ dst,
                       const float* __restrict__ temb,
                       const float* __restrict__ w1, const float* __restrict__ b1,
                       const float* __restrict__ w2, const float* __restrict__ b2,
                       float* __restrict__ ef, float* __restrict__ degf,
                       int E, int Nl){
  __shared__ float sh_h[2][32];
  int t = threadIdx.x, sub = t>>5, j = t&31;
  int e = blockIdx.x*2 + sub;
  if (e < E){
    int s_ = src[e], d_ = dst[e];
    float vx = lc[(size_t)s_*3+0]-pc[(size_t)d_*6+0];
    float vy = lc[(size_t)s_*3+1]-pc[(size_t)d_*6+1];
    float vz = lc[(size_t)s_*3+2]-pc[(size_t)d_*6+2];
    float dist = sqrtf(vx*vx+vy*vy+vz*vz+1e-12f);
    float h = b1[j] + dist*w1[j];
    for (int a=0;a<64;a++) h += temb[a]*w1[(a+1)*32+j];
    sh_h[sub][j] = silu_f(h);
  }
  __syncthreads();
  if (e < E){
    float o = b2[j];
    for (int a=0;a<32;a++) o += sh_h[sub][a]*w2[a*32+j];
    ef[(size_t)e*32+j] = o;
    if (j==0) atomicAdd(&degf[Nl + dst[e]], 1.f);
  }
}

// ---------------- ALL layers' edge MLPs upfront (ef is layer-invariant) ----------------
// out fp16: m2h[(l*E + e)*128 + t]
__global__ void k_mlp_all(const float* __restrict__ ef,
                          const float* __restrict__ w1a, const float* __restrict__ b1a,
                          const float* __restrict__ w2a, const float* __restrict__ b2a,
                          _Float16* __restrict__ m2h, int E){
  __shared__ float sh_e[32], sh_h[128];
  int bid = blockIdx.x;
  int e = bid % E, l = bid / E;
  const float* w1 = w1a + (size_t)l*32*128;
  const float* b1 = b1a + (size_t)l*128;
  const float* w2 = w2a + (size_t)l*128*128;
  const float* b2 = b2a + (size_t)l*128;
  int t = threadIdx.x;
  if (t<32) sh_e[t] = ef[(size_t)e*32+t];
  __syncthreads();
  float h = b1[t];
  for (int a=0;a<32;a++) h += sh_e[a]*w1[a*128+t];
  sh_h[t] = silu_f(h);
  __syncthreads();
  float h2 = b2[t];
  for (int a=0;a<128;a++) h2 += sh_h[a]*w2[a*128+t];
  m2h[((size_t)l*E + e)*128 + t] = (_Float16)silu_f(h2);
}

// ---------------- pack W (+bias rows) into MFMA B-fragment order, fp16 ----------------
// idx = ((((l*NKB + kblk)*3 + nt)*64 + lane)*8 + j)
// kp = kblk*32 + (lane>>4)*8 + j; o = nt*16 + (lane&15)
__global__ void k_packB(const float* __restrict__ w3, const float* __restrict__ b3,
                        _Float16* __restrict__ wbh, int L){
  int total = L*NKB*1536;
  for (int idx = blockIdx.x*blockDim.x+threadIdx.x; idx < total; idx += gridDim.x*blockDim.x){
    int j = idx & 7;
    int lane = (idx >> 3) & 63;
    int rest = idx >> 9;
    int nt = rest % 3; int rest2 = rest / 3;
    int kblk = rest2 % NKB; int l = rest2 / NKB;
    int kp = kblk*32 + ((lane>>4)<<3) + j;
    int o  = nt*16 + (lane & 15);
    float v;
    if (kp < 6144){
      int i = kp >> 7, kk = kp & 127;
      v = w3[((size_t)(l*128 + kk))*11520 + i*48 + o];
    } else {
      int ii = kp - 6144;
      v = (ii < 48) ? b3[(size_t)l*11520 + ii*48 + o] : 0.f;
    }
    wbh[idx] = (_Float16)v;
  }
}

// ---------------- hot kernel: fp16 MFMA GEMM, 64 edges x K-range per block ----------------
__global__ __launch_bounds__(128) void k_msg3(
    const _Float16* __restrict__ m2h, const float* __restrict__ s,
    const _Float16* __restrict__ wbh,   // layer base, packed B (fp16)
    const int* __restrict__ src, const int* __restrict__ dst,
    float* __restrict__ Sacc, int Nl){
  __shared__ __align__(16) _Float16 sB[2][KCH*1536];   // 2 x 12 KiB
  __shared__ __align__(16) _Float16 sm2h[64][136];     // 128 + 8 pad (bank stride 4)
  __shared__ __align__(16) _Float16 sseq[64][72];      // 48 se + zeros; stride 144B
  __shared__ int sdst[64];
  const int t = threadIdx.x, lane = t & 63, w = t >> 6;
  const int e0 = blockIdx.x * 64;
  const int by = blockIdx.y;
  const int kb0 = (NKB*by)/KSPL, kb1 = (NKB*(by+1))/KSPL;

  // stage m2 (fp16, contiguous rows -> padded LDS rows)
  for (int q = t; q < 64*16; q += 128){
    int e = q >> 4, c = q & 15;
    float4 v = *(const float4*)(m2h + ((size_t)(e0+e))*128 + c*8);
    *(float4*)&sm2h[e][c*8] = v;
  }
  // stage se as fp16, rows padded with zeros to 64 (+8 align pad)
  for (int q = t; q < 64*9; q += 128){
    int e = q/9, g = q - e*9;
    half8 hv = {};
    if (g < 6){
      const float* sp = s + (size_t)src[e0+e]*48 + g*8;
      float4 p0 = *(const float4*)sp, p1 = *(const float4*)(sp+4);
      hv[0]=(_Float16)p0.x; hv[1]=(_Float16)p0.y; hv[2]=(_Float16)p0.z; hv[3]=(_Float16)p0.w;
      hv[4]=(_Float16)p1.x; hv[5]=(_Float16)p1.y; hv[6]=(_Float16)p1.z; hv[7]=(_Float16)p1.w;
    }
    *(half8*)&sseq[e][g*8] = hv;
  }
  if (t < 64) sdst[t] = dst[e0+t];

  auto stage = [&](int c){
    int kbase = kb0 + c*KCH;
    int nk = kb1 - kbase; if (nk > KCH) nk = KCH;
    int bytes = nk*3072;
    const char* g = (const char*)wbh + (size_t)kbase*3072;
    char* lb = (char*)sB[c&1];
    for (int off = w*1024; off < bytes; off += 2048){
      __builtin_amdgcn_global_load_lds(
        (const __attribute__((address_space(1))) void*)(g + off + (size_t)lane*16),
        (__attribute__((address_space(3))) void*)(lb + off), 16, 0, 0);
    }
  };
  stage(0);

  const int m = lane & 15, quad = lane >> 4;
  const int r0 = w*32 + m, r1 = r0 + 16;
  f32x4 acc00={0.f,0.f,0.f,0.f}, acc01={0.f,0.f,0.f,0.f}, acc02={0.f,0.f,0.f,0.f};
  f32x4 acc10={0.f,0.f,0.f,0.f}, acc11={0.f,0.f,0.f,0.f}, acc12={0.f,0.f,0.f,0.f};

  const int nch = (kb1-kb0+KCH-1)/KCH;
  for (int c = 0; c < nch; c++){
    __syncthreads();              // drains stage(c) (vmcnt0 before barrier)
    if (c+1 < nch) stage(c+1);    // prefetch overlaps compute(c)
    int kbase = kb0 + c*KCH;
    int kbn = kb1 - kbase; if (kbn > KCH) kbn = KCH;
    const _Float16* bb = sB[c&1];
    for (int kk = 0; kk < kbn; kk++){
      int kblk = kbase + kk;
      half8 a0, a1;
      if (kblk < 192){
        int i = kblk >> 2;
        int base = ((kblk & 3) << 5) + quad*8;
        _Float16 sv0 = sseq[r0][i], sv1 = sseq[r1][i];
        half8 m0 = *(const half8*)&sm2h[r0][base];
        half8 m1 = *(const half8*)&sm2h[r1][base];
        half8 s0v = {sv0,sv0,sv0,sv0,sv0,sv0,sv0,sv0};
        half8 s1v = {sv1,sv1,sv1,sv1,sv1,sv1,sv1,sv1};
        a0 = m0 * s0v;            // v_pk_mul_f16 x4
        a1 = m1 * s1v;
      } else {                    // bias rows: A = se (zero-padded)
        int ib = ((kblk-192) << 5) + quad*8;
        a0 = *(const half8*)&sseq[r0][ib];
        a1 = *(const half8*)&sseq[r1][ib];
      }
      const _Float16* bk = bb + kk*1536 + lane*8;
      half8 b0 = *(const half8*)(bk);
      half8 b1 = *(const half8*)(bk + 512);
      half8 b2 = *(const half8*)(bk + 1024);
      acc00 = __builtin_amdgcn_mfma_f32_16x16x32_f16(a0, b0, acc00, 0, 0, 0);
      acc01 = __builtin_amdgcn_mfma_f32_16x16x32_f16(a0, b1, acc01, 0, 0, 0);
      acc02 = __builtin_amdgcn_mfma_f32_16x16x32_f16(a0, b2, acc02, 0, 0, 0);
      acc10 = __builtin_amdgcn_mfma_f32_16x16x32_f16(a1, b0, acc10, 0, 0, 0);
      acc11 = __builtin_amdgcn_mfma_f32_16x16x32_f16(a1, b1, acc11, 0, 0, 0);
      acc12 = __builtin_amdgcn_mfma_f32_16x16x32_f16(a1, b2, acc12, 0, 0, 0);
    }
  }
  // epilogue: D row = quad*4+r, col = m
  #pragma unroll
  for (int r = 0; r < 4; r++){
    int el0 = w*32 + quad*4 + r;
    int el1 = el0 + 16;
    float* p0 = Sacc + (size_t)(Nl + sdst[el0])*48 + m;
    float* p1 = Sacc + (size_t)(Nl + sdst[el1])*48 + m;
    atomicAdd(p0 +  0, acc00[r]*I48);
    atomicAdd(p0 + 16, acc01[r]*I48);
    atomicAdd(p0 + 32, acc02[r]*I48);
    atomicAdd(p1 +  0, acc10[r]*I48);
    atomicAdd(p1 + 16, acc11[r]*I48);
    atomicAdd(p1 + 32, acc12[r]*I48);
  }
}

// ---------------- node update: a_s = Sacc/deg + s@si_ws*I48 ; BN partials ----------------
__global__ __launch_bounds__(256) void k_node(const float* __restrict__ Sacc,
                       const float* __restrict__ degf,
                       const float* __restrict__ s, const float* __restrict__ siw,
                       float* __restrict__ a_s, float* __restrict__ bnpart, int N){
  __shared__ float sh_s[16][48];
  __shared__ float sw[2304];
  __shared__ float csum[48], csq[48];
  int t = threadIdx.x;
  int n0 = blockIdx.x*16;
  for (int q=t;q<2304;q+=256) sw[q] = siw[q];
  for (int q=t;q<768;q+=256){
    int nl=q/48, i=q-nl*48;
    sh_s[nl][i] = s[(size_t)(n0+nl)*48+i];
  }
  if (t<48){ csum[t]=0.f; csq[t]=0.f; }
  __syncthreads();
  int nl = t>>4;
  int ob = (t&15)*3;
  int n = n0+nl;
  float dg = degf[n]; if (dg < 1.f) dg = 1.f;
  float inv = 1.f/dg;
  #pragma unroll
  for (int j=0;j<3;j++){
    int o = ob+j;
    float acc = 0.f;
    for (int i=0;i<48;i++) acc += sh_s[nl][i]*sw[i*48+o];
    float a = Sacc[(size_t)n*48+o]*inv + acc*I48;
    a_s[(size_t)n*48+o] = a;
    atomicAdd(&csum[o], a);
    atomicAdd(&csq[o], a*a);
  }
  __syncthreads();
  if (t<96) bnpart[(size_t)blockIdx.x*96 + t] = (t<48) ? csum[t] : csq[t-48];
}

__global__ void k_bnfin2(const float* __restrict__ bnpart,
                         const float* __restrict__ g, const float* __restrict__ b,
                         float* __restrict__ kscale, float* __restrict__ kbias,
                         int nblk, int N){
  __shared__ float red[8][96];
  __shared__ float tot[96];
  int t = threadIdx.x;           // 768 threads
  int gg = t/96, o = t - gg*96;
  float acc = 0.f;
  for (int bk=gg; bk<nblk; bk+=8) acc += bnpart[(size_t)bk*96 + o];
  red[gg][o] = acc;
  __syncthreads();
  if (t<96){
    float s2 = 0.f;
    #pragma unroll
    for (int k=0;k<8;k++) s2 += red[k][t];
    tot[t] = s2;
  }
  __syncthreads();
  if (t<48){
    float mu  = tot[t]/(float)N;
    float var = tot[48+t]/(float)N - mu*mu;
    float r = rsqrtf(var + 1e-5f);
    float sc = g[t]*r;
    kscale[t] = sc;
    kbias[t]  = b[t] - mu*sc;
  }
}

// s += a_s*scale + bias ; also zero Sacc for next layer
__global__ void k_supd(float* __restrict__ s, float* __restrict__ Sacc,
                       const float* __restrict__ a_s,
                       const float* __restrict__ kscale, const float* __restrict__ kbias,
                       int total){
  int idx = blockIdx.x*blockDim.x+threadIdx.x;
  if (idx < total){
    int o = idx % 48;
    s[idx] += a_s[idx]*kscale[o] + kbias[o];
    Sacc[idx] = 0.f;
  }
}

// ---------------- output: [vf(=0,3), s@out_ws*I48 (256)] per ligand node ----------------
__global__ void k_out(const float* __restrict__ s, const float* __restrict__ ows,
                      float* __restrict__ out){
  __shared__ float sh_s[48];
  int n = blockIdx.x, t = threadIdx.x;
  if (t<48) sh_s[t] = s[(size_t)n*48+t];
  __syncthreads();
  float acc = 0.f;
  for (int i=0;i<48;i++) acc += sh_s[i]*ows[i*256+t];
  out[(size_t)n*259 + 3 + t] = acc*I48;
  if (t<3) out[(size_t)n*259 + t] = 0.f;
}

extern "C" void kernel_launch(void* const* d_in, const int* in_sizes, int n_in,
                              void* d_out, int out_size, void* d_ws, size_t ws_size,
                              hipStream_t stream){
  const float* protein_coords   = (const float*)d_in[0];
  const float* protein_features = (const float*)d_in[1];
  const float* ligand_coords    = (const float*)d_in[2];
  const float* ligand_features  = (const float*)d_in[3];
  const float* t_in    = (const float*)d_in[4];
  const float* te_w1   = (const float*)d_in[5];
  const float* te_b1   = (const float*)d_in[6];
  const float* te_w2   = (const float*)d_in[7];
  const float* te_b2   = (const float*)d_in[8];
  const float* te_ln_g = (const float*)d_in[9];
  const float* te_ln_b = (const float*)d_in[10];
  const float* pe_w1   = (const float*)d_in[11];
  const float* pe_b1   = (const float*)d_in[12];
  const float* pe_ln_g = (const float*)d_in[13];
  const float* pe_ln_b = (const float*)d_in[14];
  const float* pe_w2   = (const float*)d_in[15];
  const float* pe_b2   = (const float*)d_in[16];
  const float* le_w1   = (const float*)d_in[17];
  const float* le_b1   = (const float*)d_in[18];
  const float* le_ln_g = (const float*)d_in[19];
  const float* le_ln_b = (const float*)d_in[20];
  const float* le_w2   = (const float*)d_in[21];
  const float* le_b2   = (const float*)d_in[22];
  const float* sp_w    = (const float*)d_in[23];
  const float* sp_b    = (const float*)d_in[24];
  const float* emb_w   = (const float*)d_in[25];
  const float* ee_w1   = (const float*)d_in[26];
  const float* ee_b1   = (const float*)d_in[27];
  const float* ee_w2   = (const float*)d_in[28];
  const float* ee_b2   = (const float*)d_in[29];
  const float* conv_w1 = (const float*)d_in[30];
  const float* conv_b1 = (const float*)d_in[31];
  const float* conv_w2 = (const float*)d_in[32];
  const float* conv_b2 = (const float*)d_in[33];
  const float* conv_w3 = (const float*)d_in[34];
  const float* conv_b3 = (const float*)d_in[35];
  const float* bn_gs   = (const float*)d_in[36];
  const float* bn_bs   = (const float*)d_in[37];
  const float* si_ws   = (const float*)d_in[40];
  const float* out_ws  = (const float*)d_in[43];
  const int* edge_src  = (const int*)d_in[45];
  const int* edge_dst  = (const int*)d_in[46];

  int Np = in_sizes[0]/6;
  int Nl = in_sizes[2]/3;
  int E  = in_sizes[45];
  int N  = Nl+Np;
  int L  = in_sizes[36]/48;

  float* W = (float*)d_ws;
  size_t off = 0;
  auto alloc = [&](size_t n)->float*{ float* p = W+off; off += (n+63)&~(size_t)63; return p; };
  float* temb  = alloc(64);
  float* enc   = alloc((size_t)N*48);
  float* sbuf  = alloc((size_t)N*48);
  float* ef    = alloc((size_t)E*32);
  float* degf  = alloc(N);
  float* Sacc  = alloc((size_t)N*48);
  float* a_s   = alloc((size_t)N*48);
  float* bnpart= alloc((size_t)(N/16)*96);
  float* kscale= alloc(64);
  float* kbias = alloc(64);
  _Float16* m2h = (_Float16*)alloc((size_t)L*E*128/2 + 64);
  _Float16* wbh = (_Float16*)alloc((size_t)L*NKB*1536/2 + 64);

  hipMemsetAsync(degf, 0, (size_t)N*sizeof(float), stream);
  hipMemsetAsync(Sacc, 0, (size_t)N*48*sizeof(float), stream);
  k_packB<<<1024,256,0,stream>>>(conv_w3, conv_b3, wbh, L);
  k_temb<<<1,128,0,stream>>>(t_in, te_w1, te_b1, te_w2, te_b2, te_ln_g, te_ln_b, temb);
  k_enc<<<Np,128,0,stream>>>(protein_features, 96, pe_w1, pe_b1, pe_ln_g, pe_ln_b, pe_w2, pe_b2, enc, Nl);
  k_enc<<<Nl,128,0,stream>>>(ligand_features, 52, le_w1, le_b1, le_ln_g, le_ln_b, le_w2, le_b2, enc, 0);
  k_s0<<<N,64,0,stream>>>(enc, sp_w, sp_b, emb_w, sbuf);
  k_edge<<<(E+1)/2,64,0,stream>>>(ligand_coords, protein_coords, edge_src, edge_dst, temb,
                                  ee_w1, ee_b1, ee_w2, ee_b2, ef, degf, E, Nl);
  k_mlp_all<<<E*L,128,0,stream>>>(ef, conv_w1, conv_b1, conv_w2, conv_b2, m2h, E);

  dim3 mgrid(E/64, KSPL);
  for (int l=0;l<L;l++){
    k_msg3<<<mgrid,128,0,stream>>>(m2h + (size_t)l*E*128, sbuf, wbh + (size_t)l*NKB*1536,
                                   edge_src, edge_dst, Sacc, Nl);
    k_node<<<N/16,256,0,stream>>>(Sacc, degf, sbuf, si_ws + (size_t)l*2304, a_s, bnpart, N);
    k_bnfin2<<<1,768,0,stream>>>(bnpart, bn_gs + l*48, bn_bs + l*48, kscale, kbias, N/16, N);
    k_supd<<<((size_t)N*48+255)/256,256,0,stream>>>(sbuf, Sacc, a_s, kscale, kbias, N*48);
  }
  k_out<<<Nl,256,0,stream>>>(sbuf, out_ws, (float*)d_out);
}

// Round 4
// 548.335 us; speedup vs baseline: 4.0503x; 1.1886x over previous
//
#include <hip/hip_runtime.h>
#include <hip/hip_bf16.h>
#include <math.h>

#define I48 0.14433756729740643f  // 1/sqrt(48)
#define NKB 194                   // 6144 W rows + 64 bias rows, /32
#define KCH 4                     // kblks per LDS chunk (12 KiB fp16)
#define KSPL 6                    // K-split across blockIdx.y

typedef __attribute__((ext_vector_type(8))) _Float16 half8;
typedef __attribute__((ext_vector_type(4))) float f32x4;

__device__ __forceinline__ float silu_f(float x){ return x / (1.f + __expf(-x)); }

// ---------------- time embedding (1 block, 128 thr) ----------------
__global__ void k_temb(const float* __restrict__ t_in,
                       const float* __restrict__ w1, const float* __restrict__ b1,
                       const float* __restrict__ w2, const float* __restrict__ b2,
                       const float* __restrict__ g,  const float* __restrict__ b,
                       float* __restrict__ temb){
  __shared__ float emb[64], h1[128], red[128];
  __shared__ float s_mu, s_rs;
  int t = threadIdx.x;
  float tv = t_in[0];
  if (t < 64){
    int i = t & 31;
    float fr = __expf((float)i * (-9.210340371976184f/31.f));
    float a = tv * fr;
    emb[t] = (t < 32) ? sinf(a) : cosf(a);
  }
  __syncthreads();
  {
    float z = b1[t];
    for (int i=0;i<64;i++) z += emb[i]*w1[i*128+t];
    h1[t] = silu_f(z);
  }
  __syncthreads();
  float tp = 0.f;
  if (t < 64){
    tp = b2[t];
    for (int j=0;j<128;j++) tp += h1[j]*w2[j*64+t];
  }
  red[t] = (t<64)? tp : 0.f;
  __syncthreads();
  for (int st=64;st;st>>=1){ if(t<st) red[t]+=red[t+st]; __syncthreads(); }
  if (t==0) s_mu = red[0]/64.f;
  __syncthreads();
  float d = tp - s_mu;
  red[t] = (t<64)? d*d : 0.f;
  __syncthreads();
  for (int st=64;st;st>>=1){ if(t<st) red[t]+=red[t+st]; __syncthreads(); }
  if (t==0) s_rs = rsqrtf(red[0]/64.f + 1e-5f);
  __syncthreads();
  if (t<64) temb[t] = g[t]*(d*s_rs) + b[t];
}

// ---------------- node encoders: x(in_dim) -> LN128 -> silu -> 48 ----------------
__global__ void k_enc(const float* __restrict__ x, int in_dim,
                      const float* __restrict__ w1, const float* __restrict__ b1,
                      const float* __restrict__ g,  const float* __restrict__ bb,
                      const float* __restrict__ w2, const float* __restrict__ b2,
                      float* __restrict__ out, int row_off){
  __shared__ float sx[96], sh[128], red[128];
  __shared__ float s_mu, s_rs;
  int row = blockIdx.x, t = threadIdx.x;
  for (int i=t;i<in_dim;i+=128) sx[i] = x[(size_t)row*in_dim+i];
  __syncthreads();
  float z = b1[t];
  for (int i=0;i<in_dim;i++) z += sx[i]*w1[i*128+t];
  red[t]=z; __syncthreads();
  for (int st=64;st;st>>=1){ if(t<st) red[t]+=red[t+st]; __syncthreads(); }
  if(!t) s_mu = red[0]/128.f;
  __syncthreads();
  float d = z - s_mu;
  red[t]=d*d; __syncthreads();
  for (int st=64;st;st>>=1){ if(t<st) red[t]+=red[t+st]; __syncthreads(); }
  if(!t) s_rs = rsqrtf(red[0]/128.f+1e-5f);
  __syncthreads();
  float h = g[t]*(d*s_rs)+bb[t];
  sh[t] = silu_f(h);
  __syncthreads();
  if (t<48){
    float o = b2[t];
    for (int j=0;j<128;j++) o += sh[j]*w2[j*48+t];
    out[(size_t)(row_off+row)*48+t] = o;
  }
}

// ---------------- s0 = (enc @ sp_w + sp_b) @ emb_w * I48 ----------------
__global__ void k_s0(const float* __restrict__ enc, const float* __restrict__ spw,
                     const float* __restrict__ spb, const float* __restrict__ embw,
                     float* __restrict__ s){
  __shared__ float se[48], sc[48];
  int n = blockIdx.x, t = threadIdx.x;
  if (t<48) se[t] = enc[(size_t)n*48+t];
  __syncthreads();
  if (t<48){
    float c = spb[t];
    for (int i=0;i<48;i++) c += se[i]*spw[i*48+t];
    sc[t] = c;
  }
  __syncthreads();
  if (t<48){
    float v = 0.f;
    for (int i=0;i<48;i++) v += sc[i]*embw[i*48+t];
    s[(size_t)n*48+t] = v*I48;
  }
}

// ---------------- per-edge: dist -> ef(32); also degree atomics ----------------
__global__ void k_edge(const float* __restrict__ lc, const float* __restrict__ pc,
                       const int* __restrict__ src, const int* __restrict__ dst,
                       const float* __restrict__ temb,
                       const float* __restrict__ w1, const float* __restrict__ b1,
                       const float* __restrict__ w2, const float* __restrict__ b2,
                       float* __restrict__ ef, float* __restrict__ degf,
                       int E, int Nl){
  __shared__ float sh_h[2][32];
  int t = threadIdx.x, sub = t>>5, j = t&31;
  int e = blockIdx.x*2 + sub;
  if (e < E){
    int s_ = src[e], d_ = dst[e];
    float vx = lc[(size_t)s_*3+0]-pc[(size_t)d_*6+0];
    float vy = lc[(size_t)s_*3+1]-pc[(size_t)d_*6+1];
    float vz = lc[(size_t)s_*3+2]-pc[(size_t)d_*6+2];
    float dist = sqrtf(vx*vx+vy*vy+vz*vz+1e-12f);
    float h = b1[j] + dist*w1[j];
    for (int a=0;a<64;a++) h += temb[a]*w1[(a+1)*32+j];
    sh_h[sub][j] = silu_f(h);
  }
  __syncthreads();
  if (e < E){
    float o = b2[j];
    for (int a=0;a<32;a++) o += sh_h[sub][a]*w2[a*32+j];
    ef[(size_t)e*32+j] = o;
    if (j==0) atomicAdd(&degf[Nl + dst[e]], 1.f);
  }
}

// ---------------- pack conv MLP weights into MFMA B-fragment order, fp16 ----------------
// w1p[(((l*8+nt)*64+lane)*8+j)]       = w1[l][quad*8+j][nt*16+m]
// w2p[((((l*4+kb)*8+nt)*64+lane)*8+j)] = w2[l][kb*32+quad*8+j][nt*16+m]
__global__ void k_packMLP(const float* __restrict__ w1, const float* __restrict__ w2,
                          _Float16* __restrict__ w1p, _Float16* __restrict__ w2p, int L){
  int tot1 = L*8*512;
  int tot2 = L*32*512;
  int total = tot1 + tot2;
  for (int idx = blockIdx.x*blockDim.x+threadIdx.x; idx < total; idx += gridDim.x*blockDim.x){
    if (idx < tot1){
      int j = idx & 7, lane = (idx>>3)&63, rest = idx>>9;
      int nt = rest & 7, l = rest >> 3;
      int k = (lane>>4)*8 + j, o = nt*16 + (lane&15);
      w1p[idx] = (_Float16)w1[((size_t)l*32 + k)*128 + o];
    } else {
      int i2 = idx - tot1;
      int j = i2 & 7, lane = (i2>>3)&63, rest = i2>>9;
      int nt = rest & 7, kb = (rest>>3)&3, l = rest >> 5;
      int k = kb*32 + (lane>>4)*8 + j, o = nt*16 + (lane&15);
      w2p[i2] = (_Float16)w2[((size_t)l*128 + k)*128 + o];
    }
  }
}

// ---------------- edge MLP via MFMA: 64 edges x 1 layer per block ----------------
__global__ __launch_bounds__(256) void k_mlp2(
    const float* __restrict__ ef,
    const _Float16* __restrict__ w1p, const float* __restrict__ b1a,
    const _Float16* __restrict__ w2p, const float* __restrict__ b2a,
    _Float16* __restrict__ m2h, int E){
  __shared__ __align__(16) _Float16 sef[64][40];    // stride 80B (16B-mult)
  __shared__ __align__(16) _Float16 shh[64][136];   // stride 272B (16B-mult)
  __shared__ float sb1[128], sb2[128];
  const int t = threadIdx.x, lane = t & 63, w = t >> 6;
  const int e0 = blockIdx.x * 64;
  const int l  = blockIdx.y;
  const _Float16* w1l = w1p + (size_t)l*4096;
  const _Float16* w2l = w2p + (size_t)l*16384;
  if (t < 128) sb1[t] = b1a[l*128 + t];
  else         sb2[t-128] = b2a[l*128 + (t-128)];
  {
    int row = t >> 2, g = t & 3;
    const float* p = ef + ((size_t)(e0+row))*32 + g*8;
    float4 p0 = *(const float4*)p, p1 = *(const float4*)(p+4);
    half8 hv;
    hv[0]=(_Float16)p0.x; hv[1]=(_Float16)p0.y; hv[2]=(_Float16)p0.z; hv[3]=(_Float16)p0.w;
    hv[4]=(_Float16)p1.x; hv[5]=(_Float16)p1.y; hv[6]=(_Float16)p1.z; hv[7]=(_Float16)p1.w;
    *(half8*)&sef[row][g*8] = hv;
  }
  __syncthreads();
  const int m = lane & 15, quad = lane >> 4;
  const int r = w*16 + m;
  // GEMM1: h = silu(ef@w1 + b1), K=32 (one MFMA step), N=128 (8 tiles)
  half8 a1 = *(const half8*)&sef[r][quad*8];
  f32x4 acc1[8];
  #pragma unroll
  for (int nt=0; nt<8; nt++){
    half8 b = *(const half8*)(w1l + (nt*64 + lane)*8);
    f32x4 z = {0.f,0.f,0.f,0.f};
    acc1[nt] = __builtin_amdgcn_mfma_f32_16x16x32_f16(a1, b, z, 0,0,0);
  }
  #pragma unroll
  for (int nt=0; nt<8; nt++){
    float bv = sb1[nt*16 + m];
    #pragma unroll
    for (int rr=0; rr<4; rr++)
      shh[w*16 + quad*4 + rr][nt*16 + m] = (_Float16)silu_f(acc1[nt][rr] + bv);
  }
  __syncthreads();
  // GEMM2: m2 = silu(h@w2 + b2), K=128 (4 steps), N=128
  f32x4 acc2[8];
  #pragma unroll
  for (int nt=0;nt<8;nt++) acc2[nt] = (f32x4){0.f,0.f,0.f,0.f};
  #pragma unroll
  for (int kb=0; kb<4; kb++){
    half8 a2 = *(const half8*)&shh[r][kb*32 + quad*8];
    #pragma unroll
    for (int nt=0; nt<8; nt++){
      half8 b = *(const half8*)(w2l + ((size_t)(kb*8+nt)*64 + lane)*8);
      acc2[nt] = __builtin_amdgcn_mfma_f32_16x16x32_f16(a2, b, acc2[nt], 0,0,0);
    }
  }
  __syncthreads();   // all shh reads done; reuse as output staging
  #pragma unroll
  for (int nt=0; nt<8; nt++){
    float bv = sb2[nt*16 + m];
    #pragma unroll
    for (int rr=0; rr<4; rr++)
      shh[w*16 + quad*4 + rr][nt*16 + m] = (_Float16)silu_f(acc2[nt][rr] + bv);
  }
  __syncthreads();
  for (int q = t; q < 64*16; q += 256){
    int row = q >> 4, c = q & 15;
    half8 hv = *(const half8*)&shh[row][c*8];
    *(half8*)(m2h + ((size_t)l*E + e0 + row)*128 + c*8) = hv;
  }
}

// ---------------- pack W (+bias rows) into MFMA B-fragment order, fp16 ----------------
__global__ void k_packB(const float* __restrict__ w3, const float* __restrict__ b3,
                        _Float16* __restrict__ wbh, int L){
  int total = L*NKB*1536;
  for (int idx = blockIdx.x*blockDim.x+threadIdx.x; idx < total; idx += gridDim.x*blockDim.x){
    int j = idx & 7;
    int lane = (idx >> 3) & 63;
    int rest = idx >> 9;
    int nt = rest % 3; int rest2 = rest / 3;
    int kblk = rest2 % NKB; int l = rest2 / NKB;
    int kp = kblk*32 + ((lane>>4)<<3) + j;
    int o  = nt*16 + (lane & 15);
    float v;
    if (kp < 6144){
      int i = kp >> 7, kk = kp & 127;
      v = w3[((size_t)(l*128 + kk))*11520 + i*48 + o];
    } else {
      int ii = kp - 6144;
      v = (ii < 48) ? b3[(size_t)l*11520 + ii*48 + o] : 0.f;
    }
    wbh[idx] = (_Float16)v;
  }
}

// ---------------- hot kernel: fp16 MFMA GEMM, 64 edges x K-range per block ----------------
__global__ __launch_bounds__(128) void k_msg3(
    const _Float16* __restrict__ m2h, const float* __restrict__ s,
    const _Float16* __restrict__ wbh,
    const int* __restrict__ src, const int* __restrict__ dst,
    float* __restrict__ Sacc, int Nl){
  __shared__ __align__(16) _Float16 sB[2][KCH*1536];   // 2 x 12 KiB
  __shared__ __align__(16) _Float16 sm2h[64][136];
  __shared__ __align__(16) _Float16 sseq[64][72];
  __shared__ int sdst[64];
  const int t = threadIdx.x, lane = t & 63, w = t >> 6;
  const int e0 = blockIdx.x * 64;
  const int by = blockIdx.y;
  const int kb0 = (NKB*by)/KSPL, kb1 = (NKB*(by+1))/KSPL;

  for (int q = t; q < 64*16; q += 128){
    int e = q >> 4, c = q & 15;
    float4 v = *(const float4*)(m2h + ((size_t)(e0+e))*128 + c*8);
    *(float4*)&sm2h[e][c*8] = v;
  }
  for (int q = t; q < 64*9; q += 128){
    int e = q/9, g = q - e*9;
    half8 hv = {};
    if (g < 6){
      const float* sp = s + (size_t)src[e0+e]*48 + g*8;
      float4 p0 = *(const float4*)sp, p1 = *(const float4*)(sp+4);
      hv[0]=(_Float16)p0.x; hv[1]=(_Float16)p0.y; hv[2]=(_Float16)p0.z; hv[3]=(_Float16)p0.w;
      hv[4]=(_Float16)p1.x; hv[5]=(_Float16)p1.y; hv[6]=(_Float16)p1.z; hv[7]=(_Float16)p1.w;
    }
    *(half8*)&sseq[e][g*8] = hv;
  }
  if (t < 64) sdst[t] = dst[e0+t];

  auto stage = [&](int c){
    int kbase = kb0 + c*KCH;
    int nk = kb1 - kbase; if (nk > KCH) nk = KCH;
    int bytes = nk*3072;
    const char* g = (const char*)wbh + (size_t)kbase*3072;
    char* lb = (char*)sB[c&1];
    for (int off = w*1024; off < bytes; off += 2048){
      __builtin_amdgcn_global_load_lds(
        (const __attribute__((address_space(1))) void*)(g + off + (size_t)lane*16),
        (__attribute__((address_space(3))) void*)(lb + off), 16, 0, 0);
    }
  };
  stage(0);

  const int m = lane & 15, quad = lane >> 4;
  const int r0 = w*32 + m, r1 = r0 + 16;
  f32x4 acc00={0.f,0.f,0.f,0.f}, acc01={0.f,0.f,0.f,0.f}, acc02={0.f,0.f,0.f,0.f};
  f32x4 acc10={0.f,0.f,0.f,0.f}, acc11={0.f,0.f,0.f,0.f}, acc12={0.f,0.f,0.f,0.f};

  const int nch = (kb1-kb0+KCH-1)/KCH;
  for (int c = 0; c < nch; c++){
    __syncthreads();
    if (c+1 < nch) stage(c+1);
    int kbase = kb0 + c*KCH;
    int kbn = kb1 - kbase; if (kbn > KCH) kbn = KCH;
    const _Float16* bb = sB[c&1];
    for (int kk = 0; kk < kbn; kk++){
      int kblk = kbase + kk;
      half8 a0, a1;
      if (kblk < 192){
        int i = kblk >> 2;
        int base = ((kblk & 3) << 5) + quad*8;
        _Float16 sv0 = sseq[r0][i], sv1 = sseq[r1][i];
        half8 m0 = *(const half8*)&sm2h[r0][base];
        half8 m1 = *(const half8*)&sm2h[r1][base];
        half8 s0v = {sv0,sv0,sv0,sv0,sv0,sv0,sv0,sv0};
        half8 s1v = {sv1,sv1,sv1,sv1,sv1,sv1,sv1,sv1};
        a0 = m0 * s0v;
        a1 = m1 * s1v;
      } else {
        int ib = ((kblk-192) << 5) + quad*8;
        a0 = *(const half8*)&sseq[r0][ib];
        a1 = *(const half8*)&sseq[r1][ib];
      }
      const _Float16* bk = bb + kk*1536 + lane*8;
      half8 b0 = *(const half8*)(bk);
      half8 b1 = *(const half8*)(bk + 512);
      half8 b2 = *(const half8*)(bk + 1024);
      acc00 = __builtin_amdgcn_mfma_f32_16x16x32_f16(a0, b0, acc00, 0, 0, 0);
      acc01 = __builtin_amdgcn_mfma_f32_16x16x32_f16(a0, b1, acc01, 0, 0, 0);
      acc02 = __builtin_amdgcn_mfma_f32_16x16x32_f16(a0, b2, acc02, 0, 0, 0);
      acc10 = __builtin_amdgcn_mfma_f32_16x16x32_f16(a1, b0, acc10, 0, 0, 0);
      acc11 = __builtin_amdgcn_mfma_f32_16x16x32_f16(a1, b1, acc11, 0, 0, 0);
      acc12 = __builtin_amdgcn_mfma_f32_16x16x32_f16(a1, b2, acc12, 0, 0, 0);
    }
  }
  #pragma unroll
  for (int r = 0; r < 4; r++){
    int el0 = w*32 + quad*4 + r;
    int el1 = el0 + 16;
    float* p0 = Sacc + (size_t)(Nl + sdst[el0])*48 + m;
    float* p1 = Sacc + (size_t)(Nl + sdst[el1])*48 + m;
    atomicAdd(p0 +  0, acc00[r]*I48);
    atomicAdd(p0 + 16, acc01[r]*I48);
    atomicAdd(p0 + 32, acc02[r]*I48);
    atomicAdd(p1 +  0, acc10[r]*I48);
    atomicAdd(p1 + 16, acc11[r]*I48);
    atomicAdd(p1 + 32, acc12[r]*I48);
  }
}

// ---------------- node update: a_s = Sacc/deg + s@si_ws*I48 ; BN partials ----------------
__global__ __launch_bounds__(256) void k_node(const float* __restrict__ Sacc,
                       const float* __restrict__ degf,
                       const float* __restrict__ s, const float* __restrict__ siw,
                       float* __restrict__ a_s, float* __restrict__ bnpart, int N){
  __shared__ float sh_s[16][48];
  __shared__ float sw[2304];
  __shared__ float csum[48], csq[48];
  int t = threadIdx.x;
  int n0 = blockIdx.x*16;
  for (int q=t;q<2304;q+=256) sw[q] = siw[q];
  for (int q=t;q<768;q+=256){
    int nl=q/48, i=q-nl*48;
    sh_s[nl][i] = s[(size_t)(n0+nl)*48+i];
  }
  if (t<48){ csum[t]=0.f; csq[t]=0.f; }
  __syncthreads();
  int nl = t>>4;
  int ob = (t&15)*3;
  int n = n0+nl;
  float dg = degf[n]; if (dg < 1.f) dg = 1.f;
  float inv = 1.f/dg;
  #pragma unroll
  for (int j=0;j<3;j++){
    int o = ob+j;
    float acc = 0.f;
    for (int i=0;i<48;i++) acc += sh_s[nl][i]*sw[i*48+o];
    float a = Sacc[(size_t)n*48+o]*inv + acc*I48;
    a_s[(size_t)n*48+o] = a;
    atomicAdd(&csum[o], a);
    atomicAdd(&csq[o], a*a);
  }
  __syncthreads();
  if (t<96) bnpart[(size_t)blockIdx.x*96 + t] = (t<48) ? csum[t] : csq[t-48];
}

__global__ void k_bnfin2(const float* __restrict__ bnpart,
                         const float* __restrict__ g, const float* __restrict__ b,
                         float* __restrict__ kscale, float* __restrict__ kbias,
                         int nblk, int N){
  __shared__ float red[8][96];
  __shared__ float tot[96];
  int t = threadIdx.x;
  int gg = t/96, o = t - gg*96;
  float acc = 0.f;
  for (int bk=gg; bk<nblk; bk+=8) acc += bnpart[(size_t)bk*96 + o];
  red[gg][o] = acc;
  __syncthreads();
  if (t<96){
    float s2 = 0.f;
    #pragma unroll
    for (int k=0;k<8;k++) s2 += red[k][t];
    tot[t] = s2;
  }
  __syncthreads();
  if (t<48){
    float mu  = tot[t]/(float)N;
    float var = tot[48+t]/(float)N - mu*mu;
    float r = rsqrtf(var + 1e-5f);
    float sc = g[t]*r;
    kscale[t] = sc;
    kbias[t]  = b[t] - mu*sc;
  }
}

__global__ void k_supd(float* __restrict__ s, float* __restrict__ Sacc,
                       const float* __restrict__ a_s,
                       const float* __restrict__ kscale, const float* __restrict__ kbias,
                       int total){
  int idx = blockIdx.x*blockDim.x+threadIdx.x;
  if (idx < total){
    int o = idx % 48;
    s[idx] += a_s[idx]*kscale[o] + kbias[o];
    Sacc[idx] = 0.f;
  }
}

// ---------------- output ----------------
__global__ void k_out(const float* __restrict__ s, const float* __restrict__ ows,
                      float* __restrict__ out){
  __shared__ float sh_s[48];
  int n = blockIdx.x, t = threadIdx.x;
  if (t<48) sh_s[t] = s[(size_t)n*48+t];
  __syncthreads();
  float acc = 0.f;
  for (int i=0;i<48;i++) acc += sh_s[i]*ows[i*256+t];
  out[(size_t)n*259 + 3 + t] = acc*I48;
  if (t<3) out[(size_t)n*259 + t] = 0.f;
}

extern "C" void kernel_launch(void* const* d_in, const int* in_sizes, int n_in,
                              void* d_out, int out_size, void* d_ws, size_t ws_size,
                              hipStream_t stream){
  const float* protein_coords   = (const float*)d_in[0];
  const float* protein_features = (const float*)d_in[1];
  const float* ligand_coords    = (const float*)d_in[2];
  const float* ligand_features  = (const float*)d_in[3];
  const float* t_in    = (const float*)d_in[4];
  const float* te_w1   = (const float*)d_in[5];
  const float* te_b1   = (const float*)d_in[6];
  const float* te_w2   = (const float*)d_in[7];
  const float* te_b2   = (const float*)d_in[8];
  const float* te_ln_g = (const float*)d_in[9];
  const float* te_ln_b = (const float*)d_in[10];
  const float* pe_w1   = (const float*)d_in[11];
  const float* pe_b1   = (const float*)d_in[12];
  const float* pe_ln_g = (const float*)d_in[13];
  const float* pe_ln_b = (const float*)d_in[14];
  const float* pe_w2   = (const float*)d_in[15];
  const float* pe_b2   = (const float*)d_in[16];
  const float* le_w1   = (const float*)d_in[17];
  const float* le_b1   = (const float*)d_in[18];
  const float* le_ln_g = (const float*)d_in[19];
  const float* le_ln_b = (const float*)d_in[20];
  const float* le_w2   = (const float*)d_in[21];
  const float* le_b2   = (const float*)d_in[22];
  const float* sp_w    = (const float*)d_in[23];
  const float* sp_b    = (const float*)d_in[24];
  const float* emb_w   = (const float*)d_in[25];
  const float* ee_w1   = (const float*)d_in[26];
  const float* ee_b1   = (const float*)d_in[27];
  const float* ee_w2   = (const float*)d_in[28];
  const float* ee_b2   = (const float*)d_in[29];
  const float* conv_w1 = (const float*)d_in[30];
  const float* conv_b1 = (const float*)d_in[31];
  const float* conv_w2 = (const float*)d_in[32];
  const float* conv_b2 = (const float*)d_in[33];
  const float* conv_w3 = (const float*)d_in[34];
  const float* conv_b3 = (const float*)d_in[35];
  const float* bn_gs   = (const float*)d_in[36];
  const float* bn_bs   = (const float*)d_in[37];
  const float* si_ws   = (const float*)d_in[40];
  const float* out_ws  = (const float*)d_in[43];
  const int* edge_src  = (const int*)d_in[45];
  const int* edge_dst  = (const int*)d_in[46];

  int Np = in_sizes[0]/6;
  int Nl = in_sizes[2]/3;
  int E  = in_sizes[45];
  int N  = Nl+Np;
  int L  = in_sizes[36]/48;

  float* W = (float*)d_ws;
  size_t off = 0;
  auto alloc = [&](size_t n)->float*{ float* p = W+off; off += (n+63)&~(size_t)63; return p; };
  float* temb  = alloc(64);
  float* enc   = alloc((size_t)N*48);
  float* sbuf  = alloc((size_t)N*48);
  float* ef    = alloc((size_t)E*32);
  float* degf  = alloc(N);
  float* Sacc  = alloc((size_t)N*48);
  float* a_s   = alloc((size_t)N*48);
  float* bnpart= alloc((size_t)(N/16)*96);
  float* kscale= alloc(64);
  float* kbias = alloc(64);
  _Float16* m2h = (_Float16*)alloc((size_t)L*E*128/2 + 64);
  _Float16* wbh = (_Float16*)alloc((size_t)L*NKB*1536/2 + 64);
  _Float16* w1p = (_Float16*)alloc((size_t)L*4096/2 + 64);
  _Float16* w2p = (_Float16*)alloc((size_t)L*16384/2 + 64);

  hipMemsetAsync(degf, 0, (size_t)N*sizeof(float), stream);
  hipMemsetAsync(Sacc, 0, (size_t)N*48*sizeof(float), stream);
  k_packB<<<1024,256,0,stream>>>(conv_w3, conv_b3, wbh, L);
  k_packMLP<<<480,256,0,stream>>>(conv_w1, conv_w2, w1p, w2p, L);
  k_temb<<<1,128,0,stream>>>(t_in, te_w1, te_b1, te_w2, te_b2, te_ln_g, te_ln_b, temb);
  k_enc<<<Np,128,0,stream>>>(protein_features, 96, pe_w1, pe_b1, pe_ln_g, pe_ln_b, pe_w2, pe_b2, enc, Nl);
  k_enc<<<Nl,128,0,stream>>>(ligand_features, 52, le_w1, le_b1, le_ln_g, le_ln_b, le_w2, le_b2, enc, 0);
  k_s0<<<N,64,0,stream>>>(enc, sp_w, sp_b, emb_w, sbuf);
  k_edge<<<(E+1)/2,64,0,stream>>>(ligand_coords, protein_coords, edge_src, edge_dst, temb,
                                  ee_w1, ee_b1, ee_w2, ee_b2, ef, degf, E, Nl);
  dim3 mlpg(E/64, L);
  k_mlp2<<<mlpg,256,0,stream>>>(ef, w1p, conv_b1, w2p, conv_b2, m2h, E);

  dim3 mgrid(E/64, KSPL);
  for (int l=0;l<L;l++){
    k_msg3<<<mgrid,128,0,stream>>>(m2h + (size_t)l*E*128, sbuf, wbh + (size_t)l*NKB*1536,
                                   edge_src, edge_dst, Sacc, Nl);
    k_node<<<N/16,256,0,stream>>>(Sacc, degf, sbuf, si_ws + (size_t)l*2304, a_s, bnpart, N);
    k_bnfin2<<<1,768,0,stream>>>(bnpart, bn_gs + l*48, bn_bs + l*48, kscale, kbias, N/16, N);
    k_supd<<<((size_t)N*48+255)/256,256,0,stream>>>(sbuf, Sacc, a_s, kscale, kbias, N*48);
  }
  k_out<<<Nl,256,0,stream>>>(sbuf, out_ws, (float*)d_out);
}